// Round 1
// baseline (368.605 us; speedup 1.0000x reference)
//
#include <hip/hip_runtime.h>
#include <cmath>
#include <complex>
#include <algorithm>

#define TILE 256

struct PiezoConsts {
  float M1[3][3][6];   // [i][k][c]  from y1 (x1o path, w[0:2], W3J_101)
  float M2[3][3][6];   // [i][k][c]  from y2 (x1o path, w[2:4], W3J_121)
  float M3[5][3][6];   // [i][k][c]  from y3 (x2o path, w[4:6], W3J_221)
  float M4[7][3][6];   // [i][k][c]  from y4 (x3o path, w[6:8], W3J_321)
};

// ------------------- host-side constant construction --------------------
// Exact port of the reference's _cg / _q / wigner_3j in double precision.
typedef std::complex<double> cd;

static double factd(int n) {
  static const double f[11] = {1,1,2,6,24,120,720,5040,40320,362880,3628800};
  return f[n];
}

static double cg_(int j1,int m1,int j2,int m2,int j3,int m3) {
  if (m3 != m1 + m2) return 0.0;
  int vmin = std::max(std::max(-j1 + j2 + m3, -j1 + m1), 0);
  int vmax = std::min(std::min(j2 + j3 + m1, j3 - j1 + j2), j3 + m3);
  double c = std::sqrt((2*j3+1) * factd(j3+j1-j2) * factd(j3-j1+j2) * factd(j1+j2-j3)
                       * factd(j3+m3) * factd(j3-m3)
                       / (factd(j1+j2+j3+1) * factd(j1-m1) * factd(j1+m1)
                          * factd(j2-m2) * factd(j2+m2)));
  double s = 0.0;
  for (int v = vmin; v <= vmax; ++v) {
    double sgn = ((v + j2 + m2) & 1) ? -1.0 : 1.0;
    s += sgn * factd(j2+j3+m1-v) * factd(j1-m1+v)
         / (factd(v) * factd(j3-j1+j2-v) * factd(j3+m3-v) * factd(v+j1-j2-m3));
  }
  return c * s;
}

static void q_mat(int l, cd q[7][7]) {
  for (int a=0;a<7;a++) for (int b=0;b<7;b++) q[a][b] = cd(0,0);
  double s2 = 1.0/std::sqrt(2.0);
  for (int m=-l; m<0; ++m) {
    q[l+m][l-m] = cd(s2, 0);    // q[l+m, l+|m|]
    q[l+m][l+m] = cd(0, -s2);   // q[l+m, l-|m|]
  }
  q[l][l] = cd(1,0);
  for (int m=1; m<=l; ++m) {
    double sg = (m & 1) ? -1.0 : 1.0;
    q[l+m][l+m] = cd(sg*s2, 0);
    q[l+m][l-m] = cd(0, sg*s2);
  }
  cd ph(1,0); const cd mi(0,-1);
  for (int t=0;t<l;t++) ph *= mi;   // (-1j)^l
  int n = 2*l+1;
  for (int a=0;a<n;a++) for (int b=0;b<n;b++) q[a][b] *= ph;
}

static void wigner3j_(int l1,int l2,int l3,double* out) {
  int n1=2*l1+1, n2=2*l2+1, n3=2*l3+1;
  double C[7][7][7] = {};
  for (int m1=-l1;m1<=l1;m1++) for (int m2=-l2;m2<=l2;m2++) {
    int m3 = m1+m2;
    if (m3 >= -l3 && m3 <= l3)
      C[m1+l1][m2+l2][m3+l3] = cg_(l1,m1,l2,m2,l3,m3);
  }
  cd q1[7][7], q2[7][7], q3[7][7];
  q_mat(l1,q1); q_mat(l2,q2); q_mat(l3,q3);
  double nrm = 0.0;
  for (int a=0;a<n1;a++) for (int b=0;b<n2;b++) for (int c=0;c<n3;c++) {
    cd s(0,0);
    for (int i=0;i<n1;i++) for (int k=0;k<n2;k++) for (int m=0;m<n3;m++) {
      double Cv = C[i][k][m];
      if (Cv != 0.0) s += q1[i][a]*q2[k][b]*std::conj(q3[m][c])*Cv;
    }
    out[(a*n2+b)*n3+c] = s.real();
    nrm += s.real()*s.real();
  }
  nrm = std::sqrt(nrm);
  for (int t=0;t<n1*n2*n3;t++) out[t] /= nrm;
}

static void build_consts(PiezoConsts& K) {
  double W101[3*1*3], W121[3*5*3], W221[5*5*3], W321[7*5*3], W110[3*3*1], W112[3*3*5];
  wigner3j_(1,0,1,W101);
  wigner3j_(1,2,1,W121);
  wigner3j_(2,2,1,W221);
  wigner3j_(3,2,1,W321);
  wigner3j_(1,1,0,W110);
  wigner3j_(1,1,2,W112);
  double COBm[6][3][3];
  const double s5 = std::sqrt(5.0);
  for (int p=0;p<3;p++) for (int q=0;q<3;q++) {
    COBm[0][p][q] = W110[(p*3+q)*1+0];
    for (int j=0;j<5;j++) COBm[1+j][p][q] = s5 * W112[(p*3+q)*5+j];
  }
  const int IDXv[6] = {0,4,8,1,5,6};
  double T[6][6];
  for (int a=0;a<6;a++) for (int c=0;c<6;c++)
    T[a][c] = COBm[a][IDXv[c]/3][IDXv[c]%3];
  const double ALPHA = std::sqrt(3.0/8.0);
  for (int i=0;i<3;i++) for (int k=0;k<3;k++) for (int c=0;c<6;c++) {
    K.M1[i][k][c] = (float)(ALPHA * W101[(i*1+0)*3+k] * T[0][c]);
    double m2 = 0;
    for (int j=0;j<5;j++) m2 += W121[(i*5+j)*3+k] * T[1+j][c];
    K.M2[i][k][c] = (float)(ALPHA * m2);
  }
  for (int i=0;i<5;i++) for (int k=0;k<3;k++) for (int c=0;c<6;c++) {
    double m = 0;
    for (int j=0;j<5;j++) m += W221[(i*5+j)*3+k] * T[1+j][c];
    K.M3[i][k][c] = (float)(ALPHA * m);
  }
  for (int i=0;i<7;i++) for (int k=0;k<3;k++) for (int c=0;c<6;c++) {
    double m = 0;
    for (int j=0;j<5;j++) m += W321[(i*5+j)*3+k] * T[1+j][c];
    K.M4[i][k][c] = (float)(ALPHA * m);
  }
}

// ------------------------------ device kernel ------------------------------
// LDS input tile: per row, 9 needed float4 groups (cols 8-15,24-35,48-63)
// compacted to 36 floats, row stride 37 (odd -> 2-way max bank aliasing = free).
// Compacted offsets: cols 8-15 -> 0-7, cols 24-35 -> 8-19, cols 48-63 -> 20-35.
__global__ __launch_bounds__(TILE) void piezo_kernel(
    const float* __restrict__ nf, const float* __restrict__ w8,
    float* __restrict__ out, int n, PiezoConsts C)
{
  __shared__ float lds[TILE * 37];
  const int tid = threadIdx.x;
  const int rowBase = blockIdx.x * TILE;
  const int nRows = (n - rowBase < TILE) ? (n - rowBase) : TILE;

  // ---- stage: coalesced float4 loads of the 9 needed groups per row ----
  const float4* src = (const float4*)(nf + (size_t)rowBase * 64);
  const int nVec = nRows * 16;
  const int g = tid & 15;           // float4-group index within a row (fixed per thread)
  int slot;                         // compacted slot, -1 if group unneeded
  if (g == 2 || g == 3)            slot = g - 2;      // cols 8-15
  else if (g >= 6 && g <= 8)       slot = g - 4;      // cols 24-35
  else if (g >= 12)                slot = g - 7;      // cols 48-63
  else                             slot = -1;
  const int rquad = tid >> 4;
  #pragma unroll
  for (int it = 0; it < 16; ++it) {
    int idx = it * TILE + tid;
    if (slot >= 0 && idx < nVec) {
      float4 v = src[idx];
      int row = it * 16 + rquad;
      float* p = &lds[row * 37 + slot * 4];
      p[0] = v.x; p[1] = v.y; p[2] = v.z; p[3] = v.w;
    }
  }
  __syncthreads();

  // ---- compute: one thread per row ----
  float acc[3][6];
  #pragma unroll
  for (int k=0;k<3;k++)
    #pragma unroll
    for (int c=0;c<6;c++) acc[k][c] = 0.0f;

  const bool active = (rowBase + tid) < n;
  if (active) {
    const float* r = &lds[tid * 37];
    const float w0=w8[0], w1=w8[1], w2=w8[2], w3=w8[3];
    const float w4=w8[4], w5=w8[5], w6=w8[6], w7=w8[7];
    // x1o: cols 10-15 -> offs 2-7 ; x2o: cols 26-35 -> offs 10-19 ; x3o: cols 50-63 -> offs 22-35
    float y1[3], y2[3], y3[5], y4[7];
    #pragma unroll
    for (int i=0;i<3;i++) { float a=r[2+i], b=r[5+i];  y1[i]=w0*a+w1*b; y2[i]=w2*a+w3*b; }
    #pragma unroll
    for (int i=0;i<5;i++) { y3[i]=w4*r[10+i]+w5*r[15+i]; }
    #pragma unroll
    for (int i=0;i<7;i++) { y4[i]=w6*r[22+i]+w7*r[29+i]; }
    #pragma unroll
    for (int k=0;k<3;k++) {
      #pragma unroll
      for (int c=0;c<6;c++) {
        float a = 0.0f;
        #pragma unroll
        for (int i=0;i<3;i++) a += y1[i]*C.M1[i][k][c] + y2[i]*C.M2[i][k][c];
        #pragma unroll
        for (int i=0;i<5;i++) a += y3[i]*C.M3[i][k][c];
        #pragma unroll
        for (int i=0;i<7;i++) a += y4[i]*C.M4[i][k][c];
        acc[k][c] = a;
      }
    }
  }

  __syncthreads();   // input tile fully consumed; reuse LDS for output staging
  if (active) {
    float* p = &lds[tid * 19];     // stride 19 (odd) -> conflict-free
    #pragma unroll
    for (int k=0;k<3;k++)
      #pragma unroll
      for (int c=0;c<6;c++) p[k*6+c] = acc[k][c];
  }
  __syncthreads();

  // ---- coalesced output write ----
  float* dst = out + (size_t)rowBase * 18;
  const int nOut = nRows * 18;
  for (int f = tid; f < nOut; f += TILE) {
    dst[f] = lds[(f / 18) * 19 + (f % 18)];
  }
}

// ------------------------------ launcher ------------------------------
extern "C" void kernel_launch(void* const* d_in, const int* in_sizes, int n_in,
                              void* d_out, int out_size, void* d_ws, size_t ws_size,
                              hipStream_t stream) {
  const float* nf = (const float*)d_in[0];
  const float* w  = (const float*)d_in[1];
  float* out = (float*)d_out;
  const int n = in_sizes[0] / 64;

  PiezoConsts C;
  build_consts(C);   // pure host arithmetic; graph-capture safe, identical every call

  const int grid = (n + TILE - 1) / TILE;
  piezo_kernel<<<dim3(grid), dim3(TILE), 0, stream>>>(nf, w, out, n, C);
}

// Round 2
// 363.545 us; speedup vs baseline: 1.0139x; 1.0139x over previous
//
#include <hip/hip_runtime.h>
#include <cmath>
#include <complex>
#include <algorithm>

#define TILE 256

struct PiezoConsts {
  float M1[3][3][6];   // [i][k][c]  from y1 (x1o path, w[0:2], W3J_101)
  float M2[3][3][6];   // [i][k][c]  from y2 (x1o path, w[2:4], W3J_121)
  float M3[5][3][6];   // [i][k][c]  from y3 (x2o path, w[4:6], W3J_221)
  float M4[7][3][6];   // [i][k][c]  from y4 (x3o path, w[6:8], W3J_321)
};

// ------------------- host-side constant construction --------------------
// Exact port of the reference's _cg / _q / wigner_3j in double precision.
typedef std::complex<double> cd;

static double factd(int n) {
  static const double f[11] = {1,1,2,6,24,120,720,5040,40320,362880,3628800};
  return f[n];
}

static double cg_(int j1,int m1,int j2,int m2,int j3,int m3) {
  if (m3 != m1 + m2) return 0.0;
  int vmin = std::max(std::max(-j1 + j2 + m3, -j1 + m1), 0);
  int vmax = std::min(std::min(j2 + j3 + m1, j3 - j1 + j2), j3 + m3);
  double c = std::sqrt((2*j3+1) * factd(j3+j1-j2) * factd(j3-j1+j2) * factd(j1+j2-j3)
                       * factd(j3+m3) * factd(j3-m3)
                       / (factd(j1+j2+j3+1) * factd(j1-m1) * factd(j1+m1)
                          * factd(j2-m2) * factd(j2+m2)));
  double s = 0.0;
  for (int v = vmin; v <= vmax; ++v) {
    double sgn = ((v + j2 + m2) & 1) ? -1.0 : 1.0;
    s += sgn * factd(j2+j3+m1-v) * factd(j1-m1+v)
         / (factd(v) * factd(j3-j1+j2-v) * factd(j3+m3-v) * factd(v+j1-j2-m3));
  }
  return c * s;
}

static void q_mat(int l, cd q[7][7]) {
  for (int a=0;a<7;a++) for (int b=0;b<7;b++) q[a][b] = cd(0,0);
  double s2 = 1.0/std::sqrt(2.0);
  for (int m=-l; m<0; ++m) {
    q[l+m][l-m] = cd(s2, 0);    // q[l+m, l+|m|]
    q[l+m][l+m] = cd(0, -s2);   // q[l+m, l-|m|]
  }
  q[l][l] = cd(1,0);
  for (int m=1; m<=l; ++m) {
    double sg = (m & 1) ? -1.0 : 1.0;
    q[l+m][l+m] = cd(sg*s2, 0);
    q[l+m][l-m] = cd(0, sg*s2);
  }
  cd ph(1,0); const cd mi(0,-1);
  for (int t=0;t<l;t++) ph *= mi;   // (-1j)^l
  int n = 2*l+1;
  for (int a=0;a<n;a++) for (int b=0;b<n;b++) q[a][b] *= ph;
}

static void wigner3j_(int l1,int l2,int l3,double* out) {
  int n1=2*l1+1, n2=2*l2+1, n3=2*l3+1;
  double C[7][7][7] = {};
  for (int m1=-l1;m1<=l1;m1++) for (int m2=-l2;m2<=l2;m2++) {
    int m3 = m1+m2;
    if (m3 >= -l3 && m3 <= l3)
      C[m1+l1][m2+l2][m3+l3] = cg_(l1,m1,l2,m2,l3,m3);
  }
  cd q1[7][7], q2[7][7], q3[7][7];
  q_mat(l1,q1); q_mat(l2,q2); q_mat(l3,q3);
  double nrm = 0.0;
  for (int a=0;a<n1;a++) for (int b=0;b<n2;b++) for (int c=0;c<n3;c++) {
    cd s(0,0);
    for (int i=0;i<n1;i++) for (int k=0;k<n2;k++) for (int m=0;m<n3;m++) {
      double Cv = C[i][k][m];
      if (Cv != 0.0) s += q1[i][a]*q2[k][b]*std::conj(q3[m][c])*Cv;
    }
    out[(a*n2+b)*n3+c] = s.real();
    nrm += s.real()*s.real();
  }
  nrm = std::sqrt(nrm);
  for (int t=0;t<n1*n2*n3;t++) out[t] /= nrm;
}

static void build_consts(PiezoConsts& K) {
  double W101[3*1*3], W121[3*5*3], W221[5*5*3], W321[7*5*3], W110[3*3*1], W112[3*3*5];
  wigner3j_(1,0,1,W101);
  wigner3j_(1,2,1,W121);
  wigner3j_(2,2,1,W221);
  wigner3j_(3,2,1,W321);
  wigner3j_(1,1,0,W110);
  wigner3j_(1,1,2,W112);
  double COBm[6][3][3];
  const double s5 = std::sqrt(5.0);
  for (int p=0;p<3;p++) for (int q=0;q<3;q++) {
    COBm[0][p][q] = W110[(p*3+q)*1+0];
    for (int j=0;j<5;j++) COBm[1+j][p][q] = s5 * W112[(p*3+q)*5+j];
  }
  const int IDXv[6] = {0,4,8,1,5,6};
  double T[6][6];
  for (int a=0;a<6;a++) for (int c=0;c<6;c++)
    T[a][c] = COBm[a][IDXv[c]/3][IDXv[c]%3];
  const double ALPHA = std::sqrt(3.0/8.0);
  for (int i=0;i<3;i++) for (int k=0;k<3;k++) for (int c=0;c<6;c++) {
    K.M1[i][k][c] = (float)(ALPHA * W101[(i*1+0)*3+k] * T[0][c]);
    double m2 = 0;
    for (int j=0;j<5;j++) m2 += W121[(i*5+j)*3+k] * T[1+j][c];
    K.M2[i][k][c] = (float)(ALPHA * m2);
  }
  for (int i=0;i<5;i++) for (int k=0;k<3;k++) for (int c=0;c<6;c++) {
    double m = 0;
    for (int j=0;j<5;j++) m += W221[(i*5+j)*3+k] * T[1+j][c];
    K.M3[i][k][c] = (float)(ALPHA * m);
  }
  for (int i=0;i<7;i++) for (int k=0;k<3;k++) for (int c=0;c<6;c++) {
    double m = 0;
    for (int j=0;j<5;j++) m += W321[(i*5+j)*3+k] * T[1+j][c];
    K.M4[i][k][c] = (float)(ALPHA * m);
  }
}

// ------------------------------ device kernel ------------------------------
// One thread per row. Direct float4 global loads of the 9 needed groups
// (16 B/lane = coalescing sweet spot; wave working set 16 KB fits L1).
// LDS used ONLY for output coalescing: stride 19 (odd) -> conflict-free.
__global__ __launch_bounds__(TILE, 6) void piezo_kernel(
    const float* __restrict__ nf, const float* __restrict__ w8,
    float* __restrict__ out, int n, PiezoConsts C)
{
  __shared__ float lds[TILE * 19];
  const int tid = threadIdx.x;
  const int rowBase = blockIdx.x * TILE;
  const int row = rowBase + tid;
  const bool active = row < n;

  // ---- direct loads: 9 float4 groups of this thread's row ----
  float4 A, B, Cc, D, E, F, G, H, I;
  if (active) {
    const float4* src = (const float4*)(nf + (size_t)row * 64);
    A  = src[2];   // cols  8-11
    B  = src[3];   // cols 12-15
    Cc = src[6];   // cols 24-27
    D  = src[7];   // cols 28-31
    E  = src[8];   // cols 32-35
    F  = src[12];  // cols 48-51
    G  = src[13];  // cols 52-55
    H  = src[14];  // cols 56-59
    I  = src[15];  // cols 60-63
  }

  float acc[3][6];
  #pragma unroll
  for (int k=0;k<3;k++)
    #pragma unroll
    for (int c=0;c<6;c++) acc[k][c] = 0.0f;

  if (active) {
    const float w0=w8[0], w1=w8[1], w2=w8[2], w3=w8[3];
    const float w4=w8[4], w5=w8[5], w6=w8[6], w7=w8[7];
    // x1o: cols 10-15 ; x2o: cols 26-35 ; x3o: cols 50-63 (u=0 first half, u=1 second)
    const float u1a[3] = {A.z, A.w, B.x};                    // cols 10-12
    const float u1b[3] = {B.y, B.z, B.w};                    // cols 13-15
    const float u2a[5] = {Cc.z, Cc.w, D.x, D.y, D.z};        // cols 26-30
    const float u2b[5] = {D.w, E.x, E.y, E.z, E.w};          // cols 31-35
    const float u3a[7] = {F.z, F.w, G.x, G.y, G.z, G.w, H.x};// cols 50-56
    const float u3b[7] = {H.y, H.z, H.w, I.x, I.y, I.z, I.w};// cols 57-63
    float y1[3], y2[3], y3[5], y4[7];
    #pragma unroll
    for (int i=0;i<3;i++) { y1[i]=w0*u1a[i]+w1*u1b[i]; y2[i]=w2*u1a[i]+w3*u1b[i]; }
    #pragma unroll
    for (int i=0;i<5;i++) { y3[i]=w4*u2a[i]+w5*u2b[i]; }
    #pragma unroll
    for (int i=0;i<7;i++) { y4[i]=w6*u3a[i]+w7*u3b[i]; }
    #pragma unroll
    for (int k=0;k<3;k++) {
      #pragma unroll
      for (int c=0;c<6;c++) {
        float a = 0.0f;
        #pragma unroll
        for (int i=0;i<3;i++) a += y1[i]*C.M1[i][k][c] + y2[i]*C.M2[i][k][c];
        #pragma unroll
        for (int i=0;i<5;i++) a += y3[i]*C.M3[i][k][c];
        #pragma unroll
        for (int i=0;i<7;i++) a += y4[i]*C.M4[i][k][c];
        acc[k][c] = a;
      }
    }
    float* p = &lds[tid * 19];
    #pragma unroll
    for (int k=0;k<3;k++)
      #pragma unroll
      for (int c=0;c<6;c++) p[k*6+c] = acc[k][c];
  }
  __syncthreads();

  // ---- coalesced output write ----
  const int nRows = (n - rowBase < TILE) ? (n - rowBase) : TILE;
  float* dst = out + (size_t)rowBase * 18;
  const int nOut = nRows * 18;
  for (int f = tid; f < nOut; f += TILE) {
    dst[f] = lds[(f / 18) * 19 + (f % 18)];
  }
}

// ------------------------------ launcher ------------------------------
extern "C" void kernel_launch(void* const* d_in, const int* in_sizes, int n_in,
                              void* d_out, int out_size, void* d_ws, size_t ws_size,
                              hipStream_t stream) {
  const float* nf = (const float*)d_in[0];
  const float* w  = (const float*)d_in[1];
  float* out = (float*)d_out;
  const int n = in_sizes[0] / 64;

  PiezoConsts C;
  build_consts(C);   // pure host arithmetic; graph-capture safe, identical every call

  const int grid = (n + TILE - 1) / TILE;
  piezo_kernel<<<dim3(grid), dim3(TILE), 0, stream>>>(nf, w, out, n, C);
}